// Round 4
// baseline (354.499 us; speedup 1.0000x reference)
//
#include <hip/hip_runtime.h>

// Segment-sum via 2-level LDS bucket sort + gather-reduce.
// R10 (resubmit; prior round hit GPU-acquisition timeout, never measured):
// hist_rank (800K device-scope atomic-returns) and scatter_kernel
// (800K random 4B stores) are guaranteed >=~207us combined by R9's top-5
// arithmetic (every our-dispatch <119.6us, sum 351.8us). Replace them with
// an atomic-free, coalesced bucket sort:
//   bucket_hist   : per-block LDS bucket histogram -> cnt[b][blk]
//   scan_flat     : exclusive scan of cnt (bucket-major) -> global bases
//   bucket_scatter: LDS rank + LDS bucket-sorted staging -> coalesced
//                   contiguous-run writes of (row,id) records
//   bucket_csr    : per-bucket LDS row-hist/scan -> offsets + coalesced ids
// reduce_kernel unchanged from R9 for attribution.
// Constraints: N <= 65536 (bucket = row>>8, <=256 buckets), order within a
// row arbitrary (segment-sum is order-insensitive; absmax tol 0.0625).

#define CEDGE 4096        // edges per block in bucket_hist / bucket_scatter
#define WROWS 256         // rows per bucket
#define SHIFT 8
#define STCAP 8192        // bucket_csr LDS id-staging capacity (ints)

__global__ __launch_bounds__(256) void bucket_hist(
    const int* __restrict__ edge0, int* __restrict__ cnt,
    int E, int nblk, int NB)
{
    __shared__ int lh[256];
    int t = threadIdx.x, blk = blockIdx.x;
    lh[t] = 0;
    __syncthreads();
    #pragma unroll
    for (int j = 0; j < 4; ++j) {
        int idx4 = blk * 1024 + j * 256 + t;
        int base = idx4 * 4;
        if (base + 3 < E) {
            int4 r = ((const int4*)edge0)[idx4];
            atomicAdd(&lh[r.x >> SHIFT], 1);
            atomicAdd(&lh[r.y >> SHIFT], 1);
            atomicAdd(&lh[r.z >> SHIFT], 1);
            atomicAdd(&lh[r.w >> SHIFT], 1);
        } else {
            for (int i = base; i < E && i < base + 4; ++i)
                atomicAdd(&lh[edge0[i] >> SHIFT], 1);
        }
    }
    __syncthreads();
    if (t < NB) cnt[t * nblk + blk] = lh[t];
}

// Exclusive scan, in place, of M ints. Single block, 1024 threads.
__global__ __launch_bounds__(1024) void scan_flat(int* __restrict__ a, int M)
{
    __shared__ int wsums[16];
    __shared__ int carryS;
    int t = threadIdx.x, lane = t & 63, wv = t >> 6;
    if (t == 0) carryS = 0;
    __syncthreads();
    for (int base = 0; base < M; base += 1024) {
        int i = base + t;
        int v = (i < M) ? a[i] : 0;
        int inc = v;
        #pragma unroll
        for (int off = 1; off < 64; off <<= 1) {
            int u = __shfl_up(inc, off);
            if (lane >= off) inc += u;
        }
        if (lane == 63) wsums[wv] = inc;
        __syncthreads();
        int wpre = 0;
        for (int w = 0; w < wv; ++w) wpre += wsums[w];
        int c = carryS;
        if (i < M) a[i] = c + wpre + inc - v;
        __syncthreads();
        if (t == 1023) carryS = c + wpre + inc;
    }
}

__global__ __launch_bounds__(256) void bucket_scatter(
    const int* __restrict__ edge0, const int* __restrict__ cntS,
    int* __restrict__ recs /* int2[E] */, int E, int nblk, int NB)
{
    __shared__ int lh[256];      // per-bucket local counts
    __shared__ int so[256];      // staging offsets (exclusive scan of lh)
    __shared__ int gb[256];      // global record base per bucket, this block
    __shared__ int ws4[4];
    __shared__ int2 stage[CEDGE];
    int t = threadIdx.x, lane = t & 63, wv = t >> 6, blk = blockIdx.x;
    lh[t] = 0;
    if (t < NB) gb[t] = cntS[t * nblk + blk];
    __syncthreads();

    int rowR[16], rkR[16];
    #pragma unroll
    for (int j = 0; j < 4; ++j) {
        int idx4 = blk * 1024 + j * 256 + t;
        int base = idx4 * 4;
        if (base + 3 < E) {
            int4 r = ((const int4*)edge0)[idx4];
            rowR[j*4+0] = r.x; rkR[j*4+0] = atomicAdd(&lh[r.x >> SHIFT], 1);
            rowR[j*4+1] = r.y; rkR[j*4+1] = atomicAdd(&lh[r.y >> SHIFT], 1);
            rowR[j*4+2] = r.z; rkR[j*4+2] = atomicAdd(&lh[r.z >> SHIFT], 1);
            rowR[j*4+3] = r.w; rkR[j*4+3] = atomicAdd(&lh[r.w >> SHIFT], 1);
        } else {
            #pragma unroll
            for (int c = 0; c < 4; ++c) {
                int i = base + c;
                if (i < E) {
                    int rr = edge0[i];
                    rowR[j*4+c] = rr;
                    rkR[j*4+c]  = atomicAdd(&lh[rr >> SHIFT], 1);
                } else {
                    rowR[j*4+c] = -1;
                    rkR[j*4+c]  = 0;
                }
            }
        }
    }
    __syncthreads();
    // exclusive scan of lh (256 entries) -> so
    {
        int v = lh[t];
        int inc = v;
        #pragma unroll
        for (int off = 1; off < 64; off <<= 1) {
            int u = __shfl_up(inc, off);
            if (lane >= off) inc += u;
        }
        if (lane == 63) ws4[wv] = inc;
        __syncthreads();
        int wpre = 0;
        for (int w = 0; w < wv; ++w) wpre += ws4[w];
        so[t] = wpre + inc - v;
    }
    __syncthreads();
    // place records bucket-sorted into LDS staging
    #pragma unroll
    for (int k = 0; k < 16; ++k) {
        int row = rowR[k];
        if (row >= 0) {
            int b = row >> SHIFT;
            int id = blk * CEDGE + ((k >> 2) * 256 + t) * 4 + (k & 3);
            stage[so[b] + rkR[k]] = make_int2(row, id);
        }
    }
    __syncthreads();
    // linear LDS read -> contiguous-run global writes
    int Ctot = E - blk * CEDGE; if (Ctot > CEDGE) Ctot = CEDGE;
    int2* rout = (int2*)recs;
    for (int p = t; p < Ctot; p += 256) {
        int2 rec = stage[p];
        int b = rec.x >> SHIFT;
        rout[gb[b] + (p - so[b])] = rec;
    }
}

// One block per bucket: build row offsets + ids, all global IO coalesced.
__global__ __launch_bounds__(1024) void bucket_csr(
    const int* __restrict__ cntS, const int* __restrict__ recs,
    int* __restrict__ offsets, int* __restrict__ ids,
    int E, int nblk, int NB, int N)
{
    __shared__ int rowCnt[WROWS];
    __shared__ int rowFill[WROWS];
    __shared__ int rowPre[WROWS];
    __shared__ int ws4[4];
    __shared__ int stage[STCAP];
    int t = threadIdx.x, b = blockIdx.x;
    int lane = t & 63, wv = t >> 6;
    int S0 = cntS[b * nblk];
    int S1 = (b + 1 < NB) ? cntS[(b + 1) * nblk] : E;
    int cnt = S1 - S0;
    if (t < WROWS) { rowCnt[t] = 0; rowFill[t] = 0; }
    __syncthreads();
    const int2* rin = (const int2*)recs;
    for (int k = t; k < cnt; k += 1024) {
        int2 r = rin[S0 + k];
        atomicAdd(&rowCnt[r.x - (b << SHIFT)], 1);
    }
    __syncthreads();
    // scan rowCnt (all 1024 threads participate in syncs; waves>=4 scan 0s)
    int v = (t < WROWS) ? rowCnt[t] : 0;
    int inc = v;
    #pragma unroll
    for (int off = 1; off < 64; off <<= 1) {
        int u = __shfl_up(inc, off);
        if (lane >= off) inc += u;
    }
    if (lane == 63 && wv < 4) ws4[wv] = inc;
    __syncthreads();
    if (t < WROWS) {
        int wpre = 0;
        for (int w = 0; w < wv; ++w) wpre += ws4[w];
        int ex = wpre + inc - v;
        rowPre[t] = ex;
        int gr = (b << SHIFT) + t;
        if (gr < N) offsets[gr] = S0 + ex;
    }
    if (b == NB - 1 && t == 0) offsets[N] = E;
    __syncthreads();
    bool inLds = (cnt <= STCAP);
    for (int k = t; k < cnt; k += 1024) {
        int2 r = rin[S0 + k];
        int lr = r.x - (b << SHIFT);
        int pos = rowPre[lr] + atomicAdd(&rowFill[lr], 1);
        if (inLds) stage[pos] = r.y;
        else       ids[S0 + pos] = r.y;   // overflow fallback (never for uniform input)
    }
    __syncthreads();
    if (inLds)
        for (int k = t; k < cnt; k += 1024) ids[S0 + k] = stage[k];
}

// 1 wave per row. lane = 8*sub + g. Unchanged from R9.
__global__ __launch_bounds__(256) void reduce_kernel(
    const int* __restrict__ offsets, const int* __restrict__ ids,
    const float4* __restrict__ w4, float4* __restrict__ out4, int N)
{
    int row = blockIdx.x * 4 + (threadIdx.x >> 6);
    if (row >= N) return;
    int lane = threadIdx.x & 63;
    int sub = lane >> 3, g = lane & 7;
    int beg = offsets[row], end = offsets[row + 1];
    int deg = end - beg;

    float4 a0 = make_float4(0.f, 0.f, 0.f, 0.f);
    float4 a1 = make_float4(0.f, 0.f, 0.f, 0.f);

    int nloc = deg < 64 ? deg : 64;
    int myid = (lane < deg) ? ids[beg + lane] : 0;

    const float4* __restrict__ wp = w4 + g * 2;

    int full = nloc & ~15;
    for (int b = 0; b < full; b += 16) {
        int e0 = __shfl(myid, b + sub);
        int e1 = __shfl(myid, b + 8 + sub);
        float4 w00 = wp[(size_t)e0 * 16];
        float4 w01 = wp[(size_t)e0 * 16 + 1];
        float4 w10 = wp[(size_t)e1 * 16];
        float4 w11 = wp[(size_t)e1 * 16 + 1];
        a0.x += w00.x + w10.x; a0.y += w00.y + w10.y;
        a0.z += w00.z + w10.z; a0.w += w00.w + w10.w;
        a1.x += w01.x + w11.x; a1.y += w01.y + w11.y;
        a1.z += w01.z + w11.z; a1.w += w01.w + w11.w;
    }
    if (full < nloc) {
        int s0 = full + sub;
        int s1 = full + 8 + sub;
        int e0 = __shfl(myid, s0 & 63);
        int e1 = __shfl(myid, s1 & 63);
        if (s0 < nloc) {
            float4 w0 = wp[(size_t)e0 * 16];
            float4 w1 = wp[(size_t)e0 * 16 + 1];
            a0.x += w0.x; a0.y += w0.y; a0.z += w0.z; a0.w += w0.w;
            a1.x += w1.x; a1.y += w1.y; a1.z += w1.z; a1.w += w1.w;
        }
        if (s1 < nloc) {
            float4 w0 = wp[(size_t)e1 * 16];
            float4 w1 = wp[(size_t)e1 * 16 + 1];
            a0.x += w0.x; a0.y += w0.y; a0.z += w0.z; a0.w += w0.w;
            a1.x += w1.x; a1.y += w1.y; a1.z += w1.z; a1.w += w1.w;
        }
    }
    for (int j = beg + 64 + sub; j < end; j += 8) {
        int e = ids[j];
        float4 w0 = wp[(size_t)e * 16];
        float4 w1 = wp[(size_t)e * 16 + 1];
        a0.x += w0.x; a0.y += w0.y; a0.z += w0.z; a0.w += w0.w;
        a1.x += w1.x; a1.y += w1.y; a1.z += w1.z; a1.w += w1.w;
    }

    #pragma unroll
    for (int m = 8; m < 64; m <<= 1) {
        a0.x += __shfl_xor(a0.x, m); a0.y += __shfl_xor(a0.y, m);
        a0.z += __shfl_xor(a0.z, m); a0.w += __shfl_xor(a0.w, m);
        a1.x += __shfl_xor(a1.x, m); a1.y += __shfl_xor(a1.y, m);
        a1.z += __shfl_xor(a1.z, m); a1.w += __shfl_xor(a1.w, m);
    }
    if (sub == 0) {
        out4[(size_t)row * 16 + g * 2]     = a0;
        out4[(size_t)row * 16 + g * 2 + 1] = a1;
    }
}

extern "C" void kernel_launch(void* const* d_in, const int* in_sizes, int n_in,
                              void* d_out, int out_size, void* d_ws, size_t ws_size,
                              hipStream_t stream) {
    const int*   edge   = (const int*)d_in[0];     // (2,E) int32; rows = edge[0,:]
    const float* edge_w = (const float*)d_in[1];   // (E, 64) float32
    int E = in_sizes[0] / 2;
    int N = out_size / 64;
    int nblk = (E + CEDGE - 1) / CEDGE;            // 196 for E=800000
    int NB   = (N + WROWS - 1) / WROWS;            // 196 for N=50000 (<=256)

    // Workspace (ints): recs[2E] | cntS[NB*nblk] | offsets[N+1] | ids[E]
    int* recs    = (int*)d_ws;                     // int2[E], 8B-aligned at base
    int* cntS    = recs + 2 * (size_t)E;
    int* offsets = cntS + (size_t)NB * nblk;
    int* ids     = offsets + N + 1;

    bucket_hist   <<<nblk, 256, 0, stream>>>(edge, cntS, E, nblk, NB);
    scan_flat     <<<1, 1024, 0, stream>>>(cntS, NB * nblk);
    bucket_scatter<<<nblk, 256, 0, stream>>>(edge, cntS, recs, E, nblk, NB);
    bucket_csr    <<<NB, 1024, 0, stream>>>(cntS, recs, offsets, ids, E, nblk, NB, N);

    int blocksR = (N + 3) / 4;
    reduce_kernel <<<blocksR, 256, 0, stream>>>(offsets, ids, (const float4*)edge_w,
                                                (float4*)d_out, N);
}